// Round 1
// baseline (211.594 us; speedup 1.0000x reference)
//
#include <hip/hip_runtime.h>

// EmbeddingDropout: out[b,s,:] = weight[words[b,s], :] * mask[words[b,s]]
// words: (8,2048) int32; weight: (50257,768) fp32; mask: (50257,) fp32 (row-scaled)
// out: (8,2048,768) fp32.
//
// One block per token, 192 threads = 192 float4 = 768 floats = one row.
// Pure gather + scale: memory-bound, ~100 MB total traffic.

#define DIM 768
#define VEC4_PER_ROW (DIM / 4)  // 192

__global__ __launch_bounds__(VEC4_PER_ROW) void embed_dropout_kernel(
    const int* __restrict__ words,
    const float* __restrict__ weight,
    const float* __restrict__ mask,
    float* __restrict__ out) {
    const int token = blockIdx.x;
    const int idx = words[token];            // uniform per block
    const float scale = mask[idx];           // uniform per block

    const float4* __restrict__ wrow =
        (const float4*)(weight + (size_t)idx * DIM);
    float4* __restrict__ orow = (float4*)(out + (size_t)token * DIM);

    const int t = threadIdx.x;
    float4 v = wrow[t];
    v.x *= scale;
    v.y *= scale;
    v.z *= scale;
    v.w *= scale;
    orow[t] = v;
}

extern "C" void kernel_launch(void* const* d_in, const int* in_sizes, int n_in,
                              void* d_out, int out_size, void* d_ws, size_t ws_size,
                              hipStream_t stream) {
    const int* words = (const int*)d_in[0];       // (8,2048) int32
    const float* weight = (const float*)d_in[1];  // (50257,768) fp32
    const float* mask = (const float*)d_in[2];    // (50257,1) fp32
    float* out = (float*)d_out;                   // (8,2048,768) fp32

    const int n_tokens = in_sizes[0];  // 16384

    embed_dropout_kernel<<<n_tokens, VEC4_PER_ROW, 0, stream>>>(
        words, weight, mask, out);
}